// Round 16
// baseline (163.929 us; speedup 1.0000x reference)
//
#include <hip/hip_runtime.h>

#define N_NODES 100000
#define N_EDGES 1600000
#define DIN 256
#define DHID 128
#define DOUT 64

#define BSHIFT 8
#define NBUCKET ((N_NODES + 255) / 256)         // 391
#define CHUNK 2048
#define NCHUNK ((N_EDGES + CHUNK - 1) / CHUNK)  // 782

typedef __attribute__((ext_vector_type(8))) short bf16x8;
typedef __attribute__((ext_vector_type(4))) float f32x4;
typedef __attribute__((ext_vector_type(2))) float f32x2;

static __device__ __forceinline__ ushort f2bf(float f) {
  union { float f; uint u; } a; a.f = f;
  uint u = a.u;
  uint r = u + 0x7fffu + ((u >> 16) & 1u);  // RNE
  return (ushort)(r >> 16);
}

// ---- fp8 e4m3 helpers: native HW cvt when available, manual fallback ----

#if __has_builtin(__builtin_amdgcn_cvt_pk_f32_fp8) && __has_builtin(__builtin_amdgcn_cvt_pk_fp8_f32) && __has_builtin(__builtin_amdgcn_cvt_f32_fp8)
#define FP8_HW 1
#else
#define FP8_HW 0
#endif

static __device__ __forceinline__ uint f2fp8(float f) {
#if FP8_HW
  return (uint)(__builtin_amdgcn_cvt_pk_fp8_f32(f, f, 0, false) & 0xFF);
#else
  uint u = __float_as_uint(f);
  uint s = (u >> 24) & 0x80u;
  u &= 0x7FFFFFFFu;
  u += 0x7FFFFu + ((u >> 20) & 1u);
  int e = (int)(u >> 23) - 120;
  uint m = (u >> 20) & 7u;
  uint v = (e <= 0) ? 0u : ((e >= 15) ? 0x7Eu : (((uint)e << 3) | m));
  return s | v;
#endif
}

static __device__ __forceinline__ f32x2 fp8x2f(uint v) {
#if FP8_HW
  return __builtin_amdgcn_cvt_pk_f32_fp8(v, false);
#else
  uint lo = v & 0xFFu, hi = (v >> 8) & 0xFFu;
  uint mlo = lo & 0x7Fu, mhi = hi & 0x7Fu;
  uint blo = (mlo ? ((mlo << 4) + 0x3C00u) : 0u) | ((lo & 0x80u) << 8);
  uint bhi = (mhi ? ((mhi << 4) + 0x3C00u) : 0u) | ((hi & 0x80u) << 8);
  f32x2 r;
  r.x = __uint_as_float(blo << 16);
  r.y = __uint_as_float(bhi << 16);
  return r;
#endif
}

// ------------- B1: per-chunk bucket histogram (LDS atomics only) -------------

__global__ __launch_bounds__(256) void k_hist(const int* __restrict__ colp,
                                              int* __restrict__ cntmat) {
  __shared__ int h[NBUCKET];
  int c = blockIdx.x;
  for (int i = threadIdx.x; i < NBUCKET; i += 256) h[i] = 0;
  __syncthreads();
  int e0 = c * CHUNK, e1 = min(e0 + CHUNK, N_EDGES);
  for (int e = e0 + threadIdx.x; e < e1; e += 256)
    atomicAdd(&h[colp[e] >> BSHIFT], 1);
  __syncthreads();
  for (int i = threadIdx.x; i < NBUCKET; i += 256)
    cntmat[c * NBUCKET + i] = h[i];
}

// ------------- bucket totals (one block per bucket) -------------

__global__ __launch_bounds__(256) void k_buckettot(const int* __restrict__ cntmat,
                                                   int* __restrict__ btot) {
  __shared__ int s[256];
  int b = blockIdx.x, t = threadIdx.x;
  int sum = 0;
  for (int c = t; c < NCHUNK; c += 256) sum += cntmat[c * NBUCKET + b];
  s[t] = sum;
  __syncthreads();
  for (int d = 128; d > 0; d >>= 1) {
    if (t < d) s[t] += s[t + d];
    __syncthreads();
  }
  if (t == 0) btot[b] = s[0];
}

// ---- per-(chunk,bucket) bases; bucket-scan folded in (each block rescans btot) ----

__global__ __launch_bounds__(256) void k_chunkpfx(const int* __restrict__ cntmat,
                                                  const int* __restrict__ btot,
                                                  int* __restrict__ bbase,
                                                  int* __restrict__ basemat) {
  __shared__ int s[256];
  __shared__ int bb[NBUCKET + 1];
  int t = threadIdx.x;
  int b0 = 2 * t, b1 = 2 * t + 1;
  int v0 = (b0 < NBUCKET) ? btot[b0] : 0;
  int v1 = (b1 < NBUCKET) ? btot[b1] : 0;
  int ps = v0 + v1;
  s[t] = ps;
  __syncthreads();
  for (int d = 1; d < 256; d <<= 1) {
    int y = (t >= d) ? s[t - d] : 0;
    __syncthreads();
    s[t] += y;
    __syncthreads();
  }
  int ex = s[t] - ps;
  if (b0 < NBUCKET) bb[b0] = ex;
  if (b1 < NBUCKET) bb[b1] = ex + v0;
  if (t == 0) bb[NBUCKET] = N_EDGES;
  __syncthreads();
  if (blockIdx.x == 0) {
    for (int i = t; i <= NBUCKET; i += 256) bbase[i] = bb[i];
  }
  int wid = blockIdx.x * 4 + (t >> 6);
  int lane = t & 63;
  if (wid >= NBUCKET) return;
  int carry = bb[wid];
  const int NT = (NCHUNK + 63) / 64;
  for (int tt = 0; tt < NT; tt++) {
    int c = tt * 64 + lane;
    int v = (c < NCHUNK) ? cntmat[c * NBUCKET + wid] : 0;
    int incl = v;
#pragma unroll
    for (int d = 1; d < 64; d <<= 1) {
      int y = __shfl_up(incl, d, 64);
      if (lane >= d) incl += y;
    }
    if (c < NCHUNK) basemat[c * NBUCKET + wid] = carry + incl - v;
    carry += __shfl(incl, 63, 64);
  }
}

// ------------- B3: bin edges, 25-bit packed (src | localdst<<17) -------------

__global__ __launch_bounds__(256) void k_binscatter(const int* __restrict__ rowp,
                                                    const int* __restrict__ colp,
                                                    const int* __restrict__ basemat,
                                                    uint* __restrict__ packed) {
  __shared__ int lcur[NBUCKET];
  int c = blockIdx.x;
  for (int i = threadIdx.x; i < NBUCKET; i += 256)
    lcur[i] = basemat[c * NBUCKET + i];
  __syncthreads();
  int e0 = c * CHUNK, e1 = min(e0 + CHUNK, N_EDGES);
  for (int e = e0 + threadIdx.x; e < e1; e += 256) {
    int dst = colp[e], src = rowp[e];
    int pos = atomicAdd(&lcur[dst >> BSHIFT], 1);
    packed[pos] = (uint)src | ((uint)(dst & 255) << 17);
  }
}

// ------ C1: per-bucket degree count + scan -> off, dis (256 nodes/bucket) ------

__global__ __launch_bounds__(256) void k_count256(const uint* __restrict__ packed,
                                                  const int* __restrict__ bbase,
                                                  int* __restrict__ off,
                                                  float* __restrict__ dis) {
  __shared__ int cnt[256];
  __shared__ int s[256];
  int b = blockIdx.x, t = threadIdx.x;
  int node0 = b << BSHIFT;
  int nn = min(256, N_NODES - node0);
  cnt[t] = 0;
  __syncthreads();
  int r0 = bbase[b], r1 = bbase[b + 1];
  for (int r = r0 + t; r < r1; r += 256)
    atomicAdd(&cnt[packed[r] >> 17], 1);
  __syncthreads();
  int c = cnt[t];
  s[t] = c;
  __syncthreads();
  for (int d = 1; d < 256; d <<= 1) {
    int y = (t >= d) ? s[t - d] : 0;
    __syncthreads();
    s[t] += y;
    __syncthreads();
  }
  int ex = s[t] - c;
  if (t < nn) {
    off[node0 + t] = r0 + ex;
    dis[node0 + t] = rsqrtf((float)c + 1.0f);
  }
  if (b == NBUCKET - 1 && t == 0) off[N_NODES] = N_EDGES;
}

// ------ C2: placement -> ep (src17 | w15<<17), w = dis[src] fixed-point ------

__global__ __launch_bounds__(256) void k_place(const uint* __restrict__ packed,
                                               const int* __restrict__ bbase,
                                               const int* __restrict__ off,
                                               const float* __restrict__ dis,
                                               uint* __restrict__ ep) {
  __shared__ int cur[256];
  __shared__ int offl[256];
  int b = blockIdx.x, t = threadIdx.x;
  int node0 = b << BSHIFT;
  int nn = min(256, N_NODES - node0);
  cur[t] = 0;
  if (t < nn) offl[t] = off[node0 + t];
  __syncthreads();
  int r0 = bbase[b], r1 = bbase[b + 1];
  for (int r = r0 + t; r < r1; r += 256) {
    uint sd = packed[r];
    int d0 = sd >> 17;
    uint src = sd & 0x1FFFFu;
    float w = dis[src];  // L2-hot 400KB gather
    uint w15 = min((uint)(w * 32768.0f + 0.5f), 32767u);
    int pos = offl[d0] + atomicAdd(&cur[d0], 1);
    ep[pos] = src | (w15 << 17);
  }
}

// ---------------- W pre-pack into MFMA B-fragment order (bf16, merged) ----------------

__global__ void k_packW(const float* __restrict__ W1, ushort* __restrict__ Wp1,
                        const float* __restrict__ W2, ushort* __restrict__ Wp2) {
  int t = blockIdx.x * 256 + threadIdx.x;
  if (t < 8 * 8 * 64) {
    int l = t & 63, ks = (t >> 6) & 7, nt = t >> 9;
    int k0 = ks * 32 + (l >> 4) * 8;
    int n = nt * 16 + (l & 15);
    ushort* dst = Wp1 + (size_t)t * 8;
#pragma unroll
    for (int i = 0; i < 8; i++) dst[i] = f2bf(W1[(k0 + i) * DHID + n]);
  } else if (t < 8 * 8 * 64 + 4 * 4 * 64) {
    int t2 = t - 8 * 8 * 64;
    int l = t2 & 63, ks = (t2 >> 6) & 3, nt = t2 >> 8;
    int k0 = ks * 32 + (l >> 4) * 8;
    int n = nt * 16 + (l & 15);
    ushort* dst = Wp2 + (size_t)t2 * 8;
#pragma unroll
    for (int i = 0; i < 8; i++) dst[i] = f2bf(W2[(k0 + i) * DOUT + n]);
  }
}

// ------- GEMM1 (MFMA bf16): h1[N,128] fp8 = x[N,256]f32 @ W1 -------

__global__ __launch_bounds__(256) void k_gemm1(const float* __restrict__ x,
                                               const ushort* __restrict__ Wp,
                                               uchar* __restrict__ h1) {
  __shared__ uchar cs[4][16][144];  // 144B row stride
  int w = threadIdx.x >> 6, l = threadIdx.x & 63;
  int row0 = blockIdx.x * 64 + w * 16;
  bool valid = (row0 < N_NODES);  // N % 16 == 0
  if (valid) {
    f32x4 acc[8];
#pragma unroll
    for (int i = 0; i < 8; i++) acc[i] = (f32x4)(0.f);
    int arow = row0 + (l & 15);
    const float4* xg = (const float4*)(x + (size_t)arow * DIN) + (l >> 4) * 2;
    const bf16x8* wp = (const bf16x8*)Wp;
    float4 a[16];
#pragma unroll
    for (int ks = 0; ks < 8; ks++) {
      a[2 * ks]     = xg[ks * 8];
      a[2 * ks + 1] = xg[ks * 8 + 1];
    }
#pragma unroll
    for (int ks = 0; ks < 8; ks++) {
      float4 a0 = a[2 * ks];
      float4 a1 = a[2 * ks + 1];
      bf16x8 af;
      af[0] = (short)f2bf(a0.x); af[1] = (short)f2bf(a0.y);
      af[2] = (short)f2bf(a0.z); af[3] = (short)f2bf(a0.w);
      af[4] = (short)f2bf(a1.x); af[5] = (short)f2bf(a1.y);
      af[6] = (short)f2bf(a1.z); af[7] = (short)f2bf(a1.w);
#pragma unroll
      for (int nt = 0; nt < 8; nt++) {
        bf16x8 bf = wp[(nt * 8 + ks) * 64 + l];
        acc[nt] = __builtin_amdgcn_mfma_f32_16x16x32_bf16(af, bf, acc[nt], 0, 0, 0);
      }
    }
#pragma unroll
    for (int nt = 0; nt < 8; nt++)
#pragma unroll
      for (int r = 0; r < 4; r++)
        cs[w][(l >> 4) * 4 + r][nt * 16 + (l & 15)] = (uchar)f2fp8(acc[nt][r]);
  }
  __syncthreads();
  if (valid) {
    const uint4* s4 = (const uint4*)&cs[w][l >> 2][(l & 3) * 32];
    uint4* dst = (uint4*)(h1 + (size_t)(row0 + (l >> 2)) * DHID + (l & 3) * 32);
    dst[0] = s4[0]; dst[1] = s4[1];
  }
}

// ------- FUSED agg1 + GEMM2: 4-stream joint interleave, 16 gathers in flight -------
// Weights accumulate as raw w15; 2^-15 folded into the final per-node multiply.

#define AGG1_BATCH4(eX, pfx)                                                    \
  {                                                                             \
    uint p0 = ep[eX], p1 = ep[eX + 1], p2 = ep[eX + 2], p3 = ep[eX + 3];        \
    ushort v0 = h1[(size_t)(p0 & 0x1FFFFu) * 64 + lane];                        \
    ushort v1 = h1[(size_t)(p1 & 0x1FFFFu) * 64 + lane];                        \
    ushort v2 = h1[(size_t)(p2 & 0x1FFFFu) * 64 + lane];                        \
    ushort v3 = h1[(size_t)(p3 & 0x1FFFFu) * 64 + lane];                        \
    f32x2 f0 = fp8x2f(v0), f1 = fp8x2f(v1), f2 = fp8x2f(v2), f3 = fp8x2f(v3);   \
    float w0 = (float)(p0 >> 17);                                               \
    float w1 = (float)(p1 >> 17);                                               \
    float w2 = (float)(p2 >> 17);                                               \
    float w3 = (float)(p3 >> 17);                                               \
    ax##pfx = fmaf(f0.x, w0, ax##pfx); ay##pfx = fmaf(f0.y, w0, ay##pfx);       \
    ax##pfx = fmaf(f1.x, w1, ax##pfx); ay##pfx = fmaf(f1.y, w1, ay##pfx);       \
    ax##pfx = fmaf(f2.x, w2, ax##pfx); ay##pfx = fmaf(f2.y, w2, ay##pfx);       \
    ax##pfx = fmaf(f3.x, w3, ax##pfx); ay##pfx = fmaf(f3.y, w3, ay##pfx);       \
  }

#define AGG1_TAIL(eX, eX1, pfx)                                                 \
  for (; eX < eX1; eX++) {                                                      \
    uint p = ep[eX];                                                            \
    f32x2 f0 = fp8x2f(h1[(size_t)(p & 0x1FFFFu) * 64 + lane]);                  \
    float w0 = (float)(p >> 17);                                                \
    ax##pfx = fmaf(f0.x, w0, ax##pfx); ay##pfx = fmaf(f0.y, w0, ay##pfx);       \
  }

__global__ __launch_bounds__(256) void k_agg1g2(const ushort* __restrict__ h1,
                                                const int* __restrict__ off,
                                                const uint* __restrict__ ep,
                                                const float* __restrict__ dis,
                                                const float* __restrict__ b1,
                                                const ushort* __restrict__ Wp2,
                                                uchar* __restrict__ h2) {
  __shared__ ushort as[16][136];  // padded: row stride 272 B
  int w = threadIdx.x >> 6, lane = threadIdx.x & 63;
  int nb0 = blockIdx.x * 16;  // 100000 % 16 == 0
  float2 bb = ((const float2*)b1)[lane];
  int widA = nb0 + w * 4;
  float dA = dis[widA], dB = dis[widA + 1], dC = dis[widA + 2], dD = dis[widA + 3];
  f32x2 hvA = fp8x2f(h1[(size_t)widA * 64 + lane]);
  f32x2 hvB = fp8x2f(h1[(size_t)(widA + 1) * 64 + lane]);
  f32x2 hvC = fp8x2f(h1[(size_t)(widA + 2) * 64 + lane]);
  f32x2 hvD = fp8x2f(h1[(size_t)(widA + 3) * 64 + lane]);
  float sA = dA * 32768.0f, sB = dB * 32768.0f, sC = dC * 32768.0f, sD = dD * 32768.0f;
  float axA = hvA.x * sA, ayA = hvA.y * sA;
  float axB = hvB.x * sB, ayB = hvB.y * sB;
  float axC = hvC.x * sC, ayC = hvC.y * sC;
  float axD = hvD.x * sD, ayD = hvD.y * sD;
  int eA  = __builtin_amdgcn_readfirstlane(off[widA]);
  int eA1 = __builtin_amdgcn_readfirstlane(off[widA + 1]);
  int eB  = eA1;
  int eB1 = __builtin_amdgcn_readfirstlane(off[widA + 2]);
  int eC  = eB1;
  int eC1 = __builtin_amdgcn_readfirstlane(off[widA + 3]);
  int eD  = eC1;
  int eD1 = __builtin_amdgcn_readfirstlane(off[widA + 4]);
  while (eA + 4 <= eA1 && eB + 4 <= eB1 && eC + 4 <= eC1 && eD + 4 <= eD1) {
    AGG1_BATCH4(eA, A)
    AGG1_BATCH4(eB, B)
    AGG1_BATCH4(eC, C)
    AGG1_BATCH4(eD, D)
    eA += 4; eB += 4; eC += 4; eD += 4;
  }
  while (eA + 4 <= eA1 && eB + 4 <= eB1) {
    AGG1_BATCH4(eA, A)
    AGG1_BATCH4(eB, B)
    eA += 4; eB += 4;
  }
  while (eC + 4 <= eC1 && eD + 4 <= eD1) {
    AGG1_BATCH4(eC, C)
    AGG1_BATCH4(eD, D)
    eC += 4; eD += 4;
  }
  for (; eA + 4 <= eA1; eA += 4) AGG1_BATCH4(eA, A)
  for (; eB + 4 <= eB1; eB += 4) AGG1_BATCH4(eB, B)
  for (; eC + 4 <= eC1; eC += 4) AGG1_BATCH4(eC, C)
  for (; eD + 4 <= eD1; eD += 4) AGG1_BATCH4(eD, D)
  AGG1_TAIL(eA, eA1, A)
  AGG1_TAIL(eB, eB1, B)
  AGG1_TAIL(eC, eC1, C)
  AGG1_TAIL(eD, eD1, D)
  {
    float rx, ry;
    float fA = dA * 0x1p-15f, fB = dB * 0x1p-15f, fC = dC * 0x1p-15f, fD = dD * 0x1p-15f;
    rx = fmaxf(fmaf(fA, axA, bb.x), 0.f); ry = fmaxf(fmaf(fA, ayA, bb.y), 0.f);
    ((uint*)&as[w * 4 + 0][0])[lane] = (uint)f2bf(rx) | ((uint)f2bf(ry) << 16);
    rx = fmaxf(fmaf(fB, axB, bb.x), 0.f); ry = fmaxf(fmaf(fB, ayB, bb.y), 0.f);
    ((uint*)&as[w * 4 + 1][0])[lane] = (uint)f2bf(rx) | ((uint)f2bf(ry) << 16);
    rx = fmaxf(fmaf(fC, axC, bb.x), 0.f); ry = fmaxf(fmaf(fC, ayC, bb.y), 0.f);
    ((uint*)&as[w * 4 + 2][0])[lane] = (uint)f2bf(rx) | ((uint)f2bf(ry) << 16);
    rx = fmaxf(fmaf(fD, axD, bb.x), 0.f); ry = fmaxf(fmaf(fD, ayD, bb.y), 0.f);
    ((uint*)&as[w * 4 + 3][0])[lane] = (uint)f2bf(rx) | ((uint)f2bf(ry) << 16);
  }
  __syncthreads();
  f32x4 acc = (f32x4)(0.f);
  const bf16x8* wp = (const bf16x8*)Wp2;
#pragma unroll
  for (int ks = 0; ks < 4; ks++) {
    bf16x8 af = *(const bf16x8*)&as[lane & 15][ks * 32 + (lane >> 4) * 8];
    bf16x8 bf = wp[(w * 4 + ks) * 64 + lane];
    acc = __builtin_amdgcn_mfma_f32_16x16x32_bf16(af, bf, acc, 0, 0, 0);
  }
#pragma unroll
  for (int r = 0; r < 4; r++) {
    int row = (lane >> 4) * 4 + r;
    h2[(size_t)(nb0 + row) * DOUT + w * 16 + (lane & 15)] = (uchar)f2fp8(acc[r]);
  }
}

// -- agg2: 4 nodes/wave (16 lanes x 4 dims each) + bias + log_softmax --

#define AGG2_BATCH4(eX)                                                         \
  {                                                                             \
    uint p0 = ep[eX], p1 = ep[eX + 1], p2 = ep[eX + 2], p3 = ep[eX + 3];        \
    uint v0 = h2u[(size_t)(p0 & 0x1FFFFu) * 16 + q];                            \
    uint v1 = h2u[(size_t)(p1 & 0x1FFFFu) * 16 + q];                            \
    uint v2 = h2u[(size_t)(p2 & 0x1FFFFu) * 16 + q];                            \
    uint v3 = h2u[(size_t)(p3 & 0x1FFFFu) * 16 + q];                            \
    float w0 = (float)(p0 >> 17);                                               \
    float w1 = (float)(p1 >> 17);                                               \
    float w2 = (float)(p2 >> 17);                                               \
    float w3 = (float)(p3 >> 17);                                               \
    f32x2 l0 = fp8x2f(v0), h0 = fp8x2f(v0 >> 16);                               \
    f32x2 l1 = fp8x2f(v1), h1_ = fp8x2f(v1 >> 16);                              \
    f32x2 l2 = fp8x2f(v2), h2_ = fp8x2f(v2 >> 16);                              \
    f32x2 l3 = fp8x2f(v3), h3_ = fp8x2f(v3 >> 16);                              \
    a0 = fmaf(l0.x, w0, a0); a1 = fmaf(l0.y, w0, a1);                           \
    a2 = fmaf(h0.x, w0, a2); a3 = fmaf(h0.y, w0, a3);                           \
    a0 = fmaf(l1.x, w1, a0); a1 = fmaf(l1.y, w1, a1);                           \
    a2 = fmaf(h1_.x, w1, a2); a3 = fmaf(h1_.y, w1, a3);                         \
    a0 = fmaf(l2.x, w2, a0); a1 = fmaf(l2.y, w2, a1);                           \
    a2 = fmaf(h2_.x, w2, a2); a3 = fmaf(h2_.y, w2, a3);                         \
    a0 = fmaf(l3.x, w3, a0); a1 = fmaf(l3.y, w3, a1);                           \
    a2 = fmaf(h3_.x, w3, a2); a3 = fmaf(h3_.y, w3, a3);                         \
  }

__global__ __launch_bounds__(256) void k_agg2(const uint* __restrict__ h2u,
                                              const int* __restrict__ off,
                                              const uint* __restrict__ ep,
                                              const float* __restrict__ dis,
                                              const float* __restrict__ b2,
                                              float* __restrict__ out) {
  int gw   = (blockIdx.x * 256 + threadIdx.x) >> 6;  // wave id
  int lane = threadIdx.x & 63;
  int g = lane >> 4;       // node group 0..3
  int q = lane & 15;       // handles dims 4q..4q+3
  int wid = gw * 4 + g;    // N % 4 == 0 -> all waves full
  if (wid >= N_NODES) return;
  float d = dis[wid];
  uint sv = h2u[(size_t)wid * 16 + q];
  f32x2 slo = fp8x2f(sv), shi = fp8x2f(sv >> 16);
  float dS = d * 32768.0f;
  float a0 = slo.x * dS, a1 = slo.y * dS, a2 = shi.x * dS, a3 = shi.y * dS;
  int o0 = off[wid], o1 = off[wid + 1];  // uniform within 16-lane group
  int e = o0;
  for (; e + 4 <= o1; e += 4) AGG2_BATCH4(e)
  for (; e < o1; e++) {
    uint p = ep[e];
    uint v = h2u[(size_t)(p & 0x1FFFFu) * 16 + q];
    float w = (float)(p >> 17);
    f32x2 lo = fp8x2f(v), hi = fp8x2f(v >> 16);
    a0 = fmaf(lo.x, w, a0); a1 = fmaf(lo.y, w, a1);
    a2 = fmaf(hi.x, w, a2); a3 = fmaf(hi.y, w, a3);
  }
  float4 bbv = ((const float4*)b2)[q];
  float ds = d * 0x1p-15f;
  float v0 = fmaf(ds, a0, bbv.x);
  float v1 = fmaf(ds, a1, bbv.y);
  float v2 = fmaf(ds, a2, bbv.z);
  float v3 = fmaf(ds, a3, bbv.w);
  // log_softmax over 64 dims = 16 lanes x 4; xor 1,2,4,8 stays within group
  float m = fmaxf(fmaxf(v0, v1), fmaxf(v2, v3));
#pragma unroll
  for (int sft = 8; sft >= 1; sft >>= 1) m = fmaxf(m, __shfl_xor(m, sft, 64));
  float sum = expf(v0 - m) + expf(v1 - m) + expf(v2 - m) + expf(v3 - m);
#pragma unroll
  for (int sft = 8; sft >= 1; sft >>= 1) sum += __shfl_xor(sum, sft, 64);
  float ls = m + logf(sum);
  float4 o;
  o.x = v0 - ls; o.y = v1 - ls; o.z = v2 - ls; o.w = v3 - ls;
  ((float4*)out)[(size_t)wid * 16 + q] = o;
}

// ---------------- launch ----------------

extern "C" void kernel_launch(void* const* d_in, const int* in_sizes, int n_in,
                              void* d_out, int out_size, void* d_ws, size_t ws_size,
                              hipStream_t stream) {
  const float* x  = (const float*)d_in[0];
  const int*   ei = (const int*)d_in[1];
  const float* W1 = (const float*)d_in[2];
  const float* b1 = (const float*)d_in[3];
  const float* W2 = (const float*)d_in[4];
  const float* b2 = (const float*)d_in[5];
  float* out = (float*)d_out;
  const int* rowp = ei;            // sources
  const int* colp = ei + N_EDGES;  // destinations

  char* p = (char*)d_ws;
  size_t o = 0;
  auto alloc = [&](size_t bytes) -> void* {
    void* r = p + o;
    o = (o + bytes + 255) & ~(size_t)255;
    return r;
  };
  int*    off    = (int*)alloc((size_t)(N_NODES + 1) * 4);
  float*  dis    = (float*)alloc((size_t)N_NODES * 4);
  int*    cntmat = (int*)alloc((size_t)NCHUNK * NBUCKET * 4);
  int*    basemat= (int*)alloc((size_t)NCHUNK * NBUCKET * 4);
  int*    btot   = (int*)alloc((size_t)NBUCKET * 4);
  int*    bbase  = (int*)alloc((size_t)(NBUCKET + 1) * 4);
  uint*   packed = (uint*)alloc((size_t)N_EDGES * 4);
  uint*   ep     = (uint*)alloc((size_t)N_EDGES * 4);
  ushort* Wp1    = (ushort*)alloc((size_t)8 * 8 * 64 * 8 * 2);
  ushort* Wp2    = (ushort*)alloc((size_t)4 * 4 * 64 * 8 * 2);
  uchar*  h1     = (uchar*)alloc((size_t)N_NODES * DHID);   // 12.8 MB fp8
  uchar*  h2     = (uchar*)alloc((size_t)N_NODES * DOUT);   // 6.4 MB fp8

  k_hist<<<NCHUNK, 256, 0, stream>>>(colp, cntmat);
  k_buckettot<<<NBUCKET, 256, 0, stream>>>(cntmat, btot);
  k_chunkpfx<<<(NBUCKET + 3) / 4, 256, 0, stream>>>(cntmat, btot, bbase, basemat);
  k_binscatter<<<NCHUNK, 256, 0, stream>>>(rowp, colp, basemat, packed);
  k_count256<<<NBUCKET, 256, 0, stream>>>(packed, bbase, off, dis);
  k_place<<<NBUCKET, 256, 0, stream>>>(packed, bbase, off, dis, ep);
  k_packW<<<20, 256, 0, stream>>>(W1, Wp1, W2, Wp2);
  k_gemm1<<<(N_NODES + 63) / 64, 256, 0, stream>>>(x, Wp1, h1);
  k_agg1g2<<<N_NODES / 16, 256, 0, stream>>>((const ushort*)h1, off, ep, dis, b1, Wp2, h2);
  k_agg2<<<N_NODES / 16, 256, 0, stream>>>((const uint*)h2, off, ep, dis, b2, out);
}

// Round 17
// 157.791 us; speedup vs baseline: 1.0389x; 1.0389x over previous
//
#include <hip/hip_runtime.h>

#define N_NODES 100000
#define N_EDGES 1600000
#define DIN 256
#define DHID 128
#define DOUT 64

#define BSHIFT 8
#define NBUCKET ((N_NODES + 255) / 256)         // 391
#define CHUNK 4096
#define NCHUNK ((N_EDGES + CHUNK - 1) / CHUNK)  // 391

typedef __attribute__((ext_vector_type(8))) short bf16x8;
typedef __attribute__((ext_vector_type(4))) float f32x4;
typedef __attribute__((ext_vector_type(2))) float f32x2;

static __device__ __forceinline__ ushort f2bf(float f) {
  union { float f; uint u; } a; a.f = f;
  uint u = a.u;
  uint r = u + 0x7fffu + ((u >> 16) & 1u);  // RNE
  return (ushort)(r >> 16);
}

// ---- fp8 e4m3 helpers: native HW cvt when available, manual fallback ----

#if __has_builtin(__builtin_amdgcn_cvt_pk_f32_fp8) && __has_builtin(__builtin_amdgcn_cvt_pk_fp8_f32) && __has_builtin(__builtin_amdgcn_cvt_f32_fp8)
#define FP8_HW 1
#else
#define FP8_HW 0
#endif

static __device__ __forceinline__ uint f2fp8(float f) {
#if FP8_HW
  return (uint)(__builtin_amdgcn_cvt_pk_fp8_f32(f, f, 0, false) & 0xFF);
#else
  uint u = __float_as_uint(f);
  uint s = (u >> 24) & 0x80u;
  u &= 0x7FFFFFFFu;
  u += 0x7FFFFu + ((u >> 20) & 1u);
  int e = (int)(u >> 23) - 120;
  uint m = (u >> 20) & 7u;
  uint v = (e <= 0) ? 0u : ((e >= 15) ? 0x7Eu : (((uint)e << 3) | m));
  return s | v;
#endif
}

static __device__ __forceinline__ f32x2 fp8x2f(uint v) {
#if FP8_HW
  return __builtin_amdgcn_cvt_pk_f32_fp8(v, false);
#else
  uint lo = v & 0xFFu, hi = (v >> 8) & 0xFFu;
  uint mlo = lo & 0x7Fu, mhi = hi & 0x7Fu;
  uint blo = (mlo ? ((mlo << 4) + 0x3C00u) : 0u) | ((lo & 0x80u) << 8);
  uint bhi = (mhi ? ((mhi << 4) + 0x3C00u) : 0u) | ((hi & 0x80u) << 8);
  f32x2 r;
  r.x = __uint_as_float(blo << 16);
  r.y = __uint_as_float(bhi << 16);
  return r;
#endif
}

// ------------- B1: per-chunk bucket histogram (LDS atomics only) -------------

__global__ __launch_bounds__(256) void k_hist(const int* __restrict__ colp,
                                              int* __restrict__ cntmat) {
  __shared__ int h[NBUCKET];
  int c = blockIdx.x;
  for (int i = threadIdx.x; i < NBUCKET; i += 256) h[i] = 0;
  __syncthreads();
  int e0 = c * CHUNK, e1 = min(e0 + CHUNK, N_EDGES);
  for (int e = e0 + threadIdx.x; e < e1; e += 256)
    atomicAdd(&h[colp[e] >> BSHIFT], 1);
  __syncthreads();
  for (int i = threadIdx.x; i < NBUCKET; i += 256)
    cntmat[c * NBUCKET + i] = h[i];
}

// ------------- bucket totals (one block per bucket) -------------

__global__ __launch_bounds__(256) void k_buckettot(const int* __restrict__ cntmat,
                                                   int* __restrict__ btot) {
  __shared__ int s[256];
  int b = blockIdx.x, t = threadIdx.x;
  int sum = 0;
  for (int c = t; c < NCHUNK; c += 256) sum += cntmat[c * NBUCKET + b];
  s[t] = sum;
  __syncthreads();
  for (int d = 128; d > 0; d >>= 1) {
    if (t < d) s[t] += s[t + d];
    __syncthreads();
  }
  if (t == 0) btot[b] = s[0];
}

// ---- per-(chunk,bucket) bases; bucket-scan folded in (each block rescans btot) ----

__global__ __launch_bounds__(256) void k_chunkpfx(const int* __restrict__ cntmat,
                                                  const int* __restrict__ btot,
                                                  int* __restrict__ bbase,
                                                  int* __restrict__ basemat) {
  __shared__ int s[256];
  __shared__ int bb[NBUCKET + 1];
  int t = threadIdx.x;
  int b0 = 2 * t, b1 = 2 * t + 1;
  int v0 = (b0 < NBUCKET) ? btot[b0] : 0;
  int v1 = (b1 < NBUCKET) ? btot[b1] : 0;
  int ps = v0 + v1;
  s[t] = ps;
  __syncthreads();
  for (int d = 1; d < 256; d <<= 1) {
    int y = (t >= d) ? s[t - d] : 0;
    __syncthreads();
    s[t] += y;
    __syncthreads();
  }
  int ex = s[t] - ps;
  if (b0 < NBUCKET) bb[b0] = ex;
  if (b1 < NBUCKET) bb[b1] = ex + v0;
  if (t == 0) bb[NBUCKET] = N_EDGES;
  __syncthreads();
  if (blockIdx.x == 0) {
    for (int i = t; i <= NBUCKET; i += 256) bbase[i] = bb[i];
  }
  int wid = blockIdx.x * 4 + (t >> 6);
  int lane = t & 63;
  if (wid >= NBUCKET) return;
  int carry = bb[wid];
  const int NT = (NCHUNK + 63) / 64;
  for (int tt = 0; tt < NT; tt++) {
    int c = tt * 64 + lane;
    int v = (c < NCHUNK) ? cntmat[c * NBUCKET + wid] : 0;
    int incl = v;
#pragma unroll
    for (int d = 1; d < 64; d <<= 1) {
      int y = __shfl_up(incl, d, 64);
      if (lane >= d) incl += y;
    }
    if (c < NCHUNK) basemat[c * NBUCKET + wid] = carry + incl - v;
    carry += __shfl(incl, 63, 64);
  }
}

// ------------- B3: bin edges, 25-bit packed (src | localdst<<17) -------------

__global__ __launch_bounds__(256) void k_binscatter(const int* __restrict__ rowp,
                                                    const int* __restrict__ colp,
                                                    const int* __restrict__ basemat,
                                                    uint* __restrict__ packed) {
  __shared__ int lcur[NBUCKET];
  int c = blockIdx.x;
  for (int i = threadIdx.x; i < NBUCKET; i += 256)
    lcur[i] = basemat[c * NBUCKET + i];
  __syncthreads();
  int e0 = c * CHUNK, e1 = min(e0 + CHUNK, N_EDGES);
  for (int e = e0 + threadIdx.x; e < e1; e += 256) {
    int dst = colp[e], src = rowp[e];
    int pos = atomicAdd(&lcur[dst >> BSHIFT], 1);
    packed[pos] = (uint)src | ((uint)(dst & 255) << 17);
  }
}

// ------ C1: per-bucket degree count + scan -> off, dis (256 nodes/bucket) ------

__global__ __launch_bounds__(256) void k_count256(const uint* __restrict__ packed,
                                                  const int* __restrict__ bbase,
                                                  int* __restrict__ off,
                                                  float* __restrict__ dis) {
  __shared__ int cnt[256];
  __shared__ int s[256];
  int b = blockIdx.x, t = threadIdx.x;
  int node0 = b << BSHIFT;
  int nn = min(256, N_NODES - node0);
  cnt[t] = 0;
  __syncthreads();
  int r0 = bbase[b], r1 = bbase[b + 1];
  for (int r = r0 + t; r < r1; r += 256)
    atomicAdd(&cnt[packed[r] >> 17], 1);
  __syncthreads();
  int c = cnt[t];
  s[t] = c;
  __syncthreads();
  for (int d = 1; d < 256; d <<= 1) {
    int y = (t >= d) ? s[t - d] : 0;
    __syncthreads();
    s[t] += y;
    __syncthreads();
  }
  int ex = s[t] - c;
  if (t < nn) {
    off[node0 + t] = r0 + ex;
    dis[node0 + t] = rsqrtf((float)c + 1.0f);
  }
  if (b == NBUCKET - 1 && t == 0) off[N_NODES] = N_EDGES;
}

// ------ C2: placement -> ep (src17 | w15<<17), w = dis[src] fixed-point ------

__global__ __launch_bounds__(256) void k_place(const uint* __restrict__ packed,
                                               const int* __restrict__ bbase,
                                               const int* __restrict__ off,
                                               const float* __restrict__ dis,
                                               uint* __restrict__ ep) {
  __shared__ int cur[256];
  __shared__ int offl[256];
  int b = blockIdx.x, t = threadIdx.x;
  int node0 = b << BSHIFT;
  int nn = min(256, N_NODES - node0);
  cur[t] = 0;
  if (t < nn) offl[t] = off[node0 + t];
  __syncthreads();
  int r0 = bbase[b], r1 = bbase[b + 1];
  for (int r = r0 + t; r < r1; r += 256) {
    uint sd = packed[r];
    int d0 = sd >> 17;
    uint src = sd & 0x1FFFFu;
    float w = dis[src];  // L2-hot 400KB gather
    uint w15 = min((uint)(w * 32768.0f + 0.5f), 32767u);
    int pos = offl[d0] + atomicAdd(&cur[d0], 1);
    ep[pos] = src | (w15 << 17);
  }
}

// ---------------- W pre-pack into MFMA B-fragment order (bf16, merged) ----------------

__global__ void k_packW(const float* __restrict__ W1, ushort* __restrict__ Wp1,
                        const float* __restrict__ W2, ushort* __restrict__ Wp2) {
  int t = blockIdx.x * 256 + threadIdx.x;
  if (t < 8 * 8 * 64) {
    int l = t & 63, ks = (t >> 6) & 7, nt = t >> 9;
    int k0 = ks * 32 + (l >> 4) * 8;
    int n = nt * 16 + (l & 15);
    ushort* dst = Wp1 + (size_t)t * 8;
#pragma unroll
    for (int i = 0; i < 8; i++) dst[i] = f2bf(W1[(k0 + i) * DHID + n]);
  } else if (t < 8 * 8 * 64 + 4 * 4 * 64) {
    int t2 = t - 8 * 8 * 64;
    int l = t2 & 63, ks = (t2 >> 6) & 3, nt = t2 >> 8;
    int k0 = ks * 32 + (l >> 4) * 8;
    int n = nt * 16 + (l & 15);
    ushort* dst = Wp2 + (size_t)t2 * 8;
#pragma unroll
    for (int i = 0; i < 8; i++) dst[i] = f2bf(W2[(k0 + i) * DOUT + n]);
  }
}

// ------- GEMM1 (MFMA bf16): h1[N,128] fp8 = x[N,256]f32 @ W1 -------

__global__ __launch_bounds__(256) void k_gemm1(const float* __restrict__ x,
                                               const ushort* __restrict__ Wp,
                                               uchar* __restrict__ h1) {
  __shared__ uchar cs[4][16][144];  // 144B row stride
  int w = threadIdx.x >> 6, l = threadIdx.x & 63;
  int row0 = blockIdx.x * 64 + w * 16;
  bool valid = (row0 < N_NODES);  // N % 16 == 0
  if (valid) {
    f32x4 acc[8];
#pragma unroll
    for (int i = 0; i < 8; i++) acc[i] = (f32x4)(0.f);
    int arow = row0 + (l & 15);
    const float4* xg = (const float4*)(x + (size_t)arow * DIN) + (l >> 4) * 2;
    const bf16x8* wp = (const bf16x8*)Wp;
    float4 a[16];
#pragma unroll
    for (int ks = 0; ks < 8; ks++) {
      a[2 * ks]     = xg[ks * 8];
      a[2 * ks + 1] = xg[ks * 8 + 1];
    }
#pragma unroll
    for (int ks = 0; ks < 8; ks++) {
      float4 a0 = a[2 * ks];
      float4 a1 = a[2 * ks + 1];
      bf16x8 af;
      af[0] = (short)f2bf(a0.x); af[1] = (short)f2bf(a0.y);
      af[2] = (short)f2bf(a0.z); af[3] = (short)f2bf(a0.w);
      af[4] = (short)f2bf(a1.x); af[5] = (short)f2bf(a1.y);
      af[6] = (short)f2bf(a1.z); af[7] = (short)f2bf(a1.w);
#pragma unroll
      for (int nt = 0; nt < 8; nt++) {
        bf16x8 bf = wp[(nt * 8 + ks) * 64 + l];
        acc[nt] = __builtin_amdgcn_mfma_f32_16x16x32_bf16(af, bf, acc[nt], 0, 0, 0);
      }
    }
#pragma unroll
    for (int nt = 0; nt < 8; nt++)
#pragma unroll
      for (int r = 0; r < 4; r++)
        cs[w][(l >> 4) * 4 + r][nt * 16 + (l & 15)] = (uchar)f2fp8(acc[nt][r]);
  }
  __syncthreads();
  if (valid) {
    const uint4* s4 = (const uint4*)&cs[w][l >> 2][(l & 3) * 32];
    uint4* dst = (uint4*)(h1 + (size_t)(row0 + (l >> 2)) * DHID + (l & 3) * 32);
    dst[0] = s4[0]; dst[1] = s4[1];
  }
}

// ------- FUSED agg1 + GEMM2: 4-stream joint interleave, 16 gathers in flight -------
// Weights accumulate as raw w15; 2^-15 folded into the final per-node multiply.

#define AGG1_BATCH4(eX, pfx)                                                    \
  {                                                                             \
    uint p0 = ep[eX], p1 = ep[eX + 1], p2 = ep[eX + 2], p3 = ep[eX + 3];        \
    ushort v0 = h1[(size_t)(p0 & 0x1FFFFu) * 64 + lane];                        \
    ushort v1 = h1[(size_t)(p1 & 0x1FFFFu) * 64 + lane];                        \
    ushort v2 = h1[(size_t)(p2 & 0x1FFFFu) * 64 + lane];                        \
    ushort v3 = h1[(size_t)(p3 & 0x1FFFFu) * 64 + lane];                        \
    f32x2 f0 = fp8x2f(v0), f1 = fp8x2f(v1), f2 = fp8x2f(v2), f3 = fp8x2f(v3);   \
    float w0 = (float)(p0 >> 17);                                               \
    float w1 = (float)(p1 >> 17);                                               \
    float w2 = (float)(p2 >> 17);                                               \
    float w3 = (float)(p3 >> 17);                                               \
    ax##pfx = fmaf(f0.x, w0, ax##pfx); ay##pfx = fmaf(f0.y, w0, ay##pfx);       \
    ax##pfx = fmaf(f1.x, w1, ax##pfx); ay##pfx = fmaf(f1.y, w1, ay##pfx);       \
    ax##pfx = fmaf(f2.x, w2, ax##pfx); ay##pfx = fmaf(f2.y, w2, ay##pfx);       \
    ax##pfx = fmaf(f3.x, w3, ax##pfx); ay##pfx = fmaf(f3.y, w3, ay##pfx);       \
  }

#define AGG1_TAIL(eX, eX1, pfx)                                                 \
  for (; eX < eX1; eX++) {                                                      \
    uint p = ep[eX];                                                            \
    f32x2 f0 = fp8x2f(h1[(size_t)(p & 0x1FFFFu) * 64 + lane]);                  \
    float w0 = (float)(p >> 17);                                                \
    ax##pfx = fmaf(f0.x, w0, ax##pfx); ay##pfx = fmaf(f0.y, w0, ay##pfx);       \
  }

__global__ __launch_bounds__(256) void k_agg1g2(const ushort* __restrict__ h1,
                                                const int* __restrict__ off,
                                                const uint* __restrict__ ep,
                                                const float* __restrict__ dis,
                                                const float* __restrict__ b1,
                                                const ushort* __restrict__ Wp2,
                                                uchar* __restrict__ h2) {
  __shared__ ushort as[16][136];  // padded: row stride 272 B
  int w = threadIdx.x >> 6, lane = threadIdx.x & 63;
  int nb0 = blockIdx.x * 16;  // 100000 % 16 == 0
  float2 bb = ((const float2*)b1)[lane];
  int widA = nb0 + w * 4;
  float dA = dis[widA], dB = dis[widA + 1], dC = dis[widA + 2], dD = dis[widA + 3];
  f32x2 hvA = fp8x2f(h1[(size_t)widA * 64 + lane]);
  f32x2 hvB = fp8x2f(h1[(size_t)(widA + 1) * 64 + lane]);
  f32x2 hvC = fp8x2f(h1[(size_t)(widA + 2) * 64 + lane]);
  f32x2 hvD = fp8x2f(h1[(size_t)(widA + 3) * 64 + lane]);
  float sA = dA * 32768.0f, sB = dB * 32768.0f, sC = dC * 32768.0f, sD = dD * 32768.0f;
  float axA = hvA.x * sA, ayA = hvA.y * sA;
  float axB = hvB.x * sB, ayB = hvB.y * sB;
  float axC = hvC.x * sC, ayC = hvC.y * sC;
  float axD = hvD.x * sD, ayD = hvD.y * sD;
  int eA  = __builtin_amdgcn_readfirstlane(off[widA]);
  int eA1 = __builtin_amdgcn_readfirstlane(off[widA + 1]);
  int eB  = eA1;
  int eB1 = __builtin_amdgcn_readfirstlane(off[widA + 2]);
  int eC  = eB1;
  int eC1 = __builtin_amdgcn_readfirstlane(off[widA + 3]);
  int eD  = eC1;
  int eD1 = __builtin_amdgcn_readfirstlane(off[widA + 4]);
  while (eA + 4 <= eA1 && eB + 4 <= eB1 && eC + 4 <= eC1 && eD + 4 <= eD1) {
    AGG1_BATCH4(eA, A)
    AGG1_BATCH4(eB, B)
    AGG1_BATCH4(eC, C)
    AGG1_BATCH4(eD, D)
    eA += 4; eB += 4; eC += 4; eD += 4;
  }
  while (eA + 4 <= eA1 && eB + 4 <= eB1) {
    AGG1_BATCH4(eA, A)
    AGG1_BATCH4(eB, B)
    eA += 4; eB += 4;
  }
  while (eC + 4 <= eC1 && eD + 4 <= eD1) {
    AGG1_BATCH4(eC, C)
    AGG1_BATCH4(eD, D)
    eC += 4; eD += 4;
  }
  for (; eA + 4 <= eA1; eA += 4) AGG1_BATCH4(eA, A)
  for (; eB + 4 <= eB1; eB += 4) AGG1_BATCH4(eB, B)
  for (; eC + 4 <= eC1; eC += 4) AGG1_BATCH4(eC, C)
  for (; eD + 4 <= eD1; eD += 4) AGG1_BATCH4(eD, D)
  AGG1_TAIL(eA, eA1, A)
  AGG1_TAIL(eB, eB1, B)
  AGG1_TAIL(eC, eC1, C)
  AGG1_TAIL(eD, eD1, D)
  {
    float rx, ry;
    float fA = dA * 0x1p-15f, fB = dB * 0x1p-15f, fC = dC * 0x1p-15f, fD = dD * 0x1p-15f;
    rx = fmaxf(fmaf(fA, axA, bb.x), 0.f); ry = fmaxf(fmaf(fA, ayA, bb.y), 0.f);
    ((uint*)&as[w * 4 + 0][0])[lane] = (uint)f2bf(rx) | ((uint)f2bf(ry) << 16);
    rx = fmaxf(fmaf(fB, axB, bb.x), 0.f); ry = fmaxf(fmaf(fB, ayB, bb.y), 0.f);
    ((uint*)&as[w * 4 + 1][0])[lane] = (uint)f2bf(rx) | ((uint)f2bf(ry) << 16);
    rx = fmaxf(fmaf(fC, axC, bb.x), 0.f); ry = fmaxf(fmaf(fC, ayC, bb.y), 0.f);
    ((uint*)&as[w * 4 + 2][0])[lane] = (uint)f2bf(rx) | ((uint)f2bf(ry) << 16);
    rx = fmaxf(fmaf(fD, axD, bb.x), 0.f); ry = fmaxf(fmaf(fD, ayD, bb.y), 0.f);
    ((uint*)&as[w * 4 + 3][0])[lane] = (uint)f2bf(rx) | ((uint)f2bf(ry) << 16);
  }
  __syncthreads();
  f32x4 acc = (f32x4)(0.f);
  const bf16x8* wp = (const bf16x8*)Wp2;
#pragma unroll
  for (int ks = 0; ks < 4; ks++) {
    bf16x8 af = *(const bf16x8*)&as[lane & 15][ks * 32 + (lane >> 4) * 8];
    bf16x8 bf = wp[(w * 4 + ks) * 64 + lane];
    acc = __builtin_amdgcn_mfma_f32_16x16x32_bf16(af, bf, acc, 0, 0, 0);
  }
#pragma unroll
  for (int r = 0; r < 4; r++) {
    int row = (lane >> 4) * 4 + r;
    h2[(size_t)(nb0 + row) * DOUT + w * 16 + (lane & 15)] = (uchar)f2fp8(acc[r]);
  }
}

// -- agg2: 4 nodes/wave (16 lanes x 4 dims each) + bias + log_softmax --

#define AGG2_BATCH4(eX)                                                         \
  {                                                                             \
    uint p0 = ep[eX], p1 = ep[eX + 1], p2 = ep[eX + 2], p3 = ep[eX + 3];        \
    uint v0 = h2u[(size_t)(p0 & 0x1FFFFu) * 16 + q];                            \
    uint v1 = h2u[(size_t)(p1 & 0x1FFFFu) * 16 + q];                            \
    uint v2 = h2u[(size_t)(p2 & 0x1FFFFu) * 16 + q];                            \
    uint v3 = h2u[(size_t)(p3 & 0x1FFFFu) * 16 + q];                            \
    float w0 = (float)(p0 >> 17);                                               \
    float w1 = (float)(p1 >> 17);                                               \
    float w2 = (float)(p2 >> 17);                                               \
    float w3 = (float)(p3 >> 17);                                               \
    f32x2 l0 = fp8x2f(v0), h0 = fp8x2f(v0 >> 16);                               \
    f32x2 l1 = fp8x2f(v1), h1_ = fp8x2f(v1 >> 16);                              \
    f32x2 l2 = fp8x2f(v2), h2_ = fp8x2f(v2 >> 16);                              \
    f32x2 l3 = fp8x2f(v3), h3_ = fp8x2f(v3 >> 16);                              \
    a0 = fmaf(l0.x, w0, a0); a1 = fmaf(l0.y, w0, a1);                           \
    a2 = fmaf(h0.x, w0, a2); a3 = fmaf(h0.y, w0, a3);                           \
    a0 = fmaf(l1.x, w1, a0); a1 = fmaf(l1.y, w1, a1);                           \
    a2 = fmaf(h1_.x, w1, a2); a3 = fmaf(h1_.y, w1, a3);                         \
    a0 = fmaf(l2.x, w2, a0); a1 = fmaf(l2.y, w2, a1);                           \
    a2 = fmaf(h2_.x, w2, a2); a3 = fmaf(h2_.y, w2, a3);                         \
    a0 = fmaf(l3.x, w3, a0); a1 = fmaf(l3.y, w3, a1);                           \
    a2 = fmaf(h3_.x, w3, a2); a3 = fmaf(h3_.y, w3, a3);                         \
  }

__global__ __launch_bounds__(256) void k_agg2(const uint* __restrict__ h2u,
                                              const int* __restrict__ off,
                                              const uint* __restrict__ ep,
                                              const float* __restrict__ dis,
                                              const float* __restrict__ b2,
                                              float* __restrict__ out) {
  int gw   = (blockIdx.x * 256 + threadIdx.x) >> 6;  // wave id
  int lane = threadIdx.x & 63;
  int g = lane >> 4;       // node group 0..3
  int q = lane & 15;       // handles dims 4q..4q+3
  int wid = gw * 4 + g;    // N % 4 == 0 -> all waves full
  if (wid >= N_NODES) return;
  float d = dis[wid];
  uint sv = h2u[(size_t)wid * 16 + q];
  f32x2 slo = fp8x2f(sv), shi = fp8x2f(sv >> 16);
  float dS = d * 32768.0f;
  float a0 = slo.x * dS, a1 = slo.y * dS, a2 = shi.x * dS, a3 = shi.y * dS;
  int o0 = off[wid], o1 = off[wid + 1];  // uniform within 16-lane group
  int e = o0;
  for (; e + 4 <= o1; e += 4) AGG2_BATCH4(e)
  for (; e < o1; e++) {
    uint p = ep[e];
    uint v = h2u[(size_t)(p & 0x1FFFFu) * 16 + q];
    float w = (float)(p >> 17);
    f32x2 lo = fp8x2f(v), hi = fp8x2f(v >> 16);
    a0 = fmaf(lo.x, w, a0); a1 = fmaf(lo.y, w, a1);
    a2 = fmaf(hi.x, w, a2); a3 = fmaf(hi.y, w, a3);
  }
  float4 bbv = ((const float4*)b2)[q];
  float ds = d * 0x1p-15f;
  float v0 = fmaf(ds, a0, bbv.x);
  float v1 = fmaf(ds, a1, bbv.y);
  float v2 = fmaf(ds, a2, bbv.z);
  float v3 = fmaf(ds, a3, bbv.w);
  // log_softmax over 64 dims = 16 lanes x 4; xor 1,2,4,8 stays within group
  float m = fmaxf(fmaxf(v0, v1), fmaxf(v2, v3));
#pragma unroll
  for (int sft = 8; sft >= 1; sft >>= 1) m = fmaxf(m, __shfl_xor(m, sft, 64));
  float sum = expf(v0 - m) + expf(v1 - m) + expf(v2 - m) + expf(v3 - m);
#pragma unroll
  for (int sft = 8; sft >= 1; sft >>= 1) sum += __shfl_xor(sum, sft, 64);
  float ls = m + logf(sum);
  float4 o;
  o.x = v0 - ls; o.y = v1 - ls; o.z = v2 - ls; o.w = v3 - ls;
  ((float4*)out)[(size_t)wid * 16 + q] = o;
}

// ---------------- launch ----------------

extern "C" void kernel_launch(void* const* d_in, const int* in_sizes, int n_in,
                              void* d_out, int out_size, void* d_ws, size_t ws_size,
                              hipStream_t stream) {
  const float* x  = (const float*)d_in[0];
  const int*   ei = (const int*)d_in[1];
  const float* W1 = (const float*)d_in[2];
  const float* b1 = (const float*)d_in[3];
  const float* W2 = (const float*)d_in[4];
  const float* b2 = (const float*)d_in[5];
  float* out = (float*)d_out;
  const int* rowp = ei;            // sources
  const int* colp = ei + N_EDGES;  // destinations

  char* p = (char*)d_ws;
  size_t o = 0;
  auto alloc = [&](size_t bytes) -> void* {
    void* r = p + o;
    o = (o + bytes + 255) & ~(size_t)255;
    return r;
  };
  int*    off    = (int*)alloc((size_t)(N_NODES + 1) * 4);
  float*  dis    = (float*)alloc((size_t)N_NODES * 4);
  int*    cntmat = (int*)alloc((size_t)NCHUNK * NBUCKET * 4);
  int*    basemat= (int*)alloc((size_t)NCHUNK * NBUCKET * 4);
  int*    btot   = (int*)alloc((size_t)NBUCKET * 4);
  int*    bbase  = (int*)alloc((size_t)(NBUCKET + 1) * 4);
  uint*   packed = (uint*)alloc((size_t)N_EDGES * 4);
  uint*   ep     = (uint*)alloc((size_t)N_EDGES * 4);
  ushort* Wp1    = (ushort*)alloc((size_t)8 * 8 * 64 * 8 * 2);
  ushort* Wp2    = (ushort*)alloc((size_t)4 * 4 * 64 * 8 * 2);
  uchar*  h1     = (uchar*)alloc((size_t)N_NODES * DHID);   // 12.8 MB fp8
  uchar*  h2     = (uchar*)alloc((size_t)N_NODES * DOUT);   // 6.4 MB fp8

  k_hist<<<NCHUNK, 256, 0, stream>>>(colp, cntmat);
  k_buckettot<<<NBUCKET, 256, 0, stream>>>(cntmat, btot);
  k_chunkpfx<<<(NBUCKET + 3) / 4, 256, 0, stream>>>(cntmat, btot, bbase, basemat);
  k_binscatter<<<NCHUNK, 256, 0, stream>>>(rowp, colp, basemat, packed);
  k_count256<<<NBUCKET, 256, 0, stream>>>(packed, bbase, off, dis);
  k_place<<<NBUCKET, 256, 0, stream>>>(packed, bbase, off, dis, ep);
  k_packW<<<20, 256, 0, stream>>>(W1, Wp1, W2, Wp2);
  k_gemm1<<<(N_NODES + 63) / 64, 256, 0, stream>>>(x, Wp1, h1);
  k_agg1g2<<<N_NODES / 16, 256, 0, stream>>>((const ushort*)h1, off, ep, dis, b1, Wp2, h2);
  k_agg2<<<N_NODES / 16, 256, 0, stream>>>((const uint*)h2, off, ep, dis, b2, out);
}

// Round 19
// 154.875 us; speedup vs baseline: 1.0585x; 1.0188x over previous
//
#include <hip/hip_runtime.h>

#define N_NODES 100000
#define N_EDGES 1600000
#define DIN 256
#define DHID 128
#define DOUT 64

#define BSHIFT 8
#define NBUCKET ((N_NODES + 255) / 256)         // 391
#define CHUNK 4096
#define NCHUNK ((N_EDGES + CHUNK - 1) / CHUNK)  // 391

#define GEMM1_NB ((N_NODES + 63) / 64)          // 1563
// gemm1 slice sizes fused into the sort pipeline (sum == GEMM1_NB)
#define G_HIST 350
#define G_BINS 600
#define G_CNT  300
#define G_PLC  313

typedef __attribute__((ext_vector_type(8))) short bf16x8;
typedef __attribute__((ext_vector_type(4))) float f32x4;
typedef __attribute__((ext_vector_type(2))) float f32x2;

static __device__ __forceinline__ ushort f2bf(float f) {
  union { float f; uint u; } a; a.f = f;
  uint u = a.u;
  uint r = u + 0x7fffu + ((u >> 16) & 1u);  // RNE
  return (ushort)(r >> 16);
}

// ---- fp8 e4m3 helpers: native HW cvt when available, manual fallback ----

#if __has_builtin(__builtin_amdgcn_cvt_pk_f32_fp8) && __has_builtin(__builtin_amdgcn_cvt_pk_fp8_f32) && __has_builtin(__builtin_amdgcn_cvt_f32_fp8)
#define FP8_HW 1
#else
#define FP8_HW 0
#endif

static __device__ __forceinline__ uint f2fp8(float f) {
#if FP8_HW
  return (uint)(__builtin_amdgcn_cvt_pk_fp8_f32(f, f, 0, false) & 0xFF);
#else
  uint u = __float_as_uint(f);
  uint s = (u >> 24) & 0x80u;
  u &= 0x7FFFFFFFu;
  u += 0x7FFFFu + ((u >> 20) & 1u);
  int e = (int)(u >> 23) - 120;
  uint m = (u >> 20) & 7u;
  uint v = (e <= 0) ? 0u : ((e >= 15) ? 0x7Eu : (((uint)e << 3) | m));
  return s | v;
#endif
}

static __device__ __forceinline__ f32x2 fp8x2f(uint v) {
#if FP8_HW
  return __builtin_amdgcn_cvt_pk_f32_fp8(v, false);
#else
  uint lo = v & 0xFFu, hi = (v >> 8) & 0xFFu;
  uint mlo = lo & 0x7Fu, mhi = hi & 0x7Fu;
  uint blo = (mlo ? ((mlo << 4) + 0x3C00u) : 0u) | ((lo & 0x80u) << 8);
  uint bhi = (mhi ? ((mhi << 4) + 0x3C00u) : 0u) | ((hi & 0x80u) << 8);
  f32x2 r;
  r.x = __uint_as_float(blo << 16);
  r.y = __uint_as_float(bhi << 16);
  return r;
#endif
}

// ---------------- gemm1 body as a device function (fused into sort kernels) ----------------
// h1[N,128] fp8 = x[N,256]f32 @ W1 ; gb = gemm block id in [0, GEMM1_NB)

static __device__ __forceinline__ void gemm1_body(int gb, const float* __restrict__ x,
                                                  const ushort* __restrict__ Wp,
                                                  uchar* __restrict__ h1,
                                                  uchar (*cs)[16][144]) {
  int w = threadIdx.x >> 6, l = threadIdx.x & 63;
  int row0 = gb * 64 + w * 16;
  bool valid = (row0 < N_NODES);  // N % 16 == 0
  if (valid) {
    f32x4 acc[8];
#pragma unroll
    for (int i = 0; i < 8; i++) acc[i] = (f32x4)(0.f);
    int arow = row0 + (l & 15);
    const float4* xg = (const float4*)(x + (size_t)arow * DIN) + (l >> 4) * 2;
    const bf16x8* wp = (const bf16x8*)Wp;
    float4 a[16];
#pragma unroll
    for (int ks = 0; ks < 8; ks++) {
      a[2 * ks]     = xg[ks * 8];
      a[2 * ks + 1] = xg[ks * 8 + 1];
    }
#pragma unroll
    for (int ks = 0; ks < 8; ks++) {
      float4 a0 = a[2 * ks];
      float4 a1 = a[2 * ks + 1];
      bf16x8 af;
      af[0] = (short)f2bf(a0.x); af[1] = (short)f2bf(a0.y);
      af[2] = (short)f2bf(a0.z); af[3] = (short)f2bf(a0.w);
      af[4] = (short)f2bf(a1.x); af[5] = (short)f2bf(a1.y);
      af[6] = (short)f2bf(a1.z); af[7] = (short)f2bf(a1.w);
#pragma unroll
      for (int nt = 0; nt < 8; nt++) {
        bf16x8 bf = wp[(nt * 8 + ks) * 64 + l];
        acc[nt] = __builtin_amdgcn_mfma_f32_16x16x32_bf16(af, bf, acc[nt], 0, 0, 0);
      }
    }
#pragma unroll
    for (int nt = 0; nt < 8; nt++)
#pragma unroll
      for (int r = 0; r < 4; r++)
        cs[w][(l >> 4) * 4 + r][nt * 16 + (l & 15)] = (uchar)f2fp8(acc[nt][r]);
  }
  __syncthreads();
  if (valid) {
    const uint4* s4 = (const uint4*)&cs[w][l >> 2][(l & 3) * 32];
    uint4* dst = (uint4*)(h1 + (size_t)(row0 + (l >> 2)) * DHID + (l & 3) * 32);
    dst[0] = s4[0]; dst[1] = s4[1];
  }
}

// ------------- B1 + gemm slice: per-chunk bucket histogram -------------

__global__ __launch_bounds__(256) void k_hist_g(const int* __restrict__ colp,
                                                int* __restrict__ cntmat,
                                                const float* __restrict__ x,
                                                const ushort* __restrict__ Wp,
                                                uchar* __restrict__ h1) {
  __shared__ int h[NBUCKET];
  __shared__ uchar cs[4][16][144];
  if (blockIdx.x >= NCHUNK) {
    gemm1_body(blockIdx.x - NCHUNK + 0, x, Wp, h1, cs);
    return;
  }
  int c = blockIdx.x;
  for (int i = threadIdx.x; i < NBUCKET; i += 256) h[i] = 0;
  __syncthreads();
  int e0 = c * CHUNK, e1 = min(e0 + CHUNK, N_EDGES);
  for (int e = e0 + threadIdx.x; e < e1; e += 256)
    atomicAdd(&h[colp[e] >> BSHIFT], 1);
  __syncthreads();
  for (int i = threadIdx.x; i < NBUCKET; i += 256)
    cntmat[c * NBUCKET + i] = h[i];
}

// ------------- bucket totals (one block per bucket) -------------

__global__ __launch_bounds__(256) void k_buckettot(const int* __restrict__ cntmat,
                                                   int* __restrict__ btot) {
  __shared__ int s[256];
  int b = blockIdx.x, t = threadIdx.x;
  int sum = 0;
  for (int c = t; c < NCHUNK; c += 256) sum += cntmat[c * NBUCKET + b];
  s[t] = sum;
  __syncthreads();
  for (int d = 128; d > 0; d >>= 1) {
    if (t < d) s[t] += s[t + d];
    __syncthreads();
  }
  if (t == 0) btot[b] = s[0];
}

// ---- per-(chunk,bucket) bases; bucket-scan folded in (each block rescans btot) ----

__global__ __launch_bounds__(256) void k_chunkpfx(const int* __restrict__ cntmat,
                                                  const int* __restrict__ btot,
                                                  int* __restrict__ bbase,
                                                  int* __restrict__ basemat) {
  __shared__ int s[256];
  __shared__ int bb[NBUCKET + 1];
  int t = threadIdx.x;
  int b0 = 2 * t, b1 = 2 * t + 1;
  int v0 = (b0 < NBUCKET) ? btot[b0] : 0;
  int v1 = (b1 < NBUCKET) ? btot[b1] : 0;
  int ps = v0 + v1;
  s[t] = ps;
  __syncthreads();
  for (int d = 1; d < 256; d <<= 1) {
    int y = (t >= d) ? s[t - d] : 0;
    __syncthreads();
    s[t] += y;
    __syncthreads();
  }
  int ex = s[t] - ps;
  if (b0 < NBUCKET) bb[b0] = ex;
  if (b1 < NBUCKET) bb[b1] = ex + v0;
  if (t == 0) bb[NBUCKET] = N_EDGES;
  __syncthreads();
  if (blockIdx.x == 0) {
    for (int i = t; i <= NBUCKET; i += 256) bbase[i] = bb[i];
  }
  int wid = blockIdx.x * 4 + (t >> 6);
  int lane = t & 63;
  if (wid >= NBUCKET) return;
  int carry = bb[wid];
  const int NT = (NCHUNK + 63) / 64;
  for (int tt = 0; tt < NT; tt++) {
    int c = tt * 64 + lane;
    int v = (c < NCHUNK) ? cntmat[c * NBUCKET + wid] : 0;
    int incl = v;
#pragma unroll
    for (int d = 1; d < 64; d <<= 1) {
      int y = __shfl_up(incl, d, 64);
      if (lane >= d) incl += y;
    }
    if (c < NCHUNK) basemat[c * NBUCKET + wid] = carry + incl - v;
    carry += __shfl(incl, 63, 64);
  }
}

// ------------- B3 + gemm slice: bin edges, packed (src | localdst<<17) -------------

__global__ __launch_bounds__(256) void k_binscatter_g(const int* __restrict__ rowp,
                                                      const int* __restrict__ colp,
                                                      const int* __restrict__ basemat,
                                                      uint* __restrict__ packed,
                                                      const float* __restrict__ x,
                                                      const ushort* __restrict__ Wp,
                                                      uchar* __restrict__ h1) {
  __shared__ int lcur[NBUCKET];
  __shared__ uchar cs[4][16][144];
  if (blockIdx.x >= NCHUNK) {
    gemm1_body(blockIdx.x - NCHUNK + G_HIST, x, Wp, h1, cs);
    return;
  }
  int c = blockIdx.x;
  for (int i = threadIdx.x; i < NBUCKET; i += 256)
    lcur[i] = basemat[c * NBUCKET + i];
  __syncthreads();
  int e0 = c * CHUNK, e1 = min(e0 + CHUNK, N_EDGES);
  for (int e = e0 + threadIdx.x; e < e1; e += 256) {
    int dst = colp[e], src = rowp[e];
    int pos = atomicAdd(&lcur[dst >> BSHIFT], 1);
    packed[pos] = (uint)src | ((uint)(dst & 255) << 17);
  }
}

// ------ C1 + gemm slice: per-bucket degree count + scan -> off, dis ------

__global__ __launch_bounds__(256) void k_count256_g(const uint* __restrict__ packed,
                                                    const int* __restrict__ bbase,
                                                    int* __restrict__ off,
                                                    float* __restrict__ dis,
                                                    const float* __restrict__ x,
                                                    const ushort* __restrict__ Wp,
                                                    uchar* __restrict__ h1) {
  __shared__ int cnt[256];
  __shared__ int s[256];
  __shared__ uchar cs[4][16][144];
  if (blockIdx.x >= NBUCKET) {
    gemm1_body(blockIdx.x - NBUCKET + G_HIST + G_BINS, x, Wp, h1, cs);
    return;
  }
  int b = blockIdx.x, t = threadIdx.x;
  int node0 = b << BSHIFT;
  int nn = min(256, N_NODES - node0);
  cnt[t] = 0;
  __syncthreads();
  int r0 = bbase[b], r1 = bbase[b + 1];
  for (int r = r0 + t; r < r1; r += 256)
    atomicAdd(&cnt[packed[r] >> 17], 1);
  __syncthreads();
  int c = cnt[t];
  s[t] = c;
  __syncthreads();
  for (int d = 1; d < 256; d <<= 1) {
    int y = (t >= d) ? s[t - d] : 0;
    __syncthreads();
    s[t] += y;
    __syncthreads();
  }
  int ex = s[t] - c;
  if (t < nn) {
    off[node0 + t] = r0 + ex;
    dis[node0 + t] = rsqrtf((float)c + 1.0f);
  }
  if (b == NBUCKET - 1 && t == 0) off[N_NODES] = N_EDGES;
}

// ------ C2 + gemm slice: placement -> ep (src17 | w15<<17) ------

__global__ __launch_bounds__(256) void k_place_g(const uint* __restrict__ packed,
                                                 const int* __restrict__ bbase,
                                                 const int* __restrict__ off,
                                                 const float* __restrict__ dis,
                                                 uint* __restrict__ ep,
                                                 const float* __restrict__ x,
                                                 const ushort* __restrict__ Wp,
                                                 uchar* __restrict__ h1) {
  __shared__ int cur[256];
  __shared__ int offl[256];
  __shared__ uchar cs[4][16][144];
  if (blockIdx.x >= NBUCKET) {
    gemm1_body(blockIdx.x - NBUCKET + G_HIST + G_BINS + G_CNT, x, Wp, h1, cs);
    return;
  }
  int b = blockIdx.x, t = threadIdx.x;
  int node0 = b << BSHIFT;
  int nn = min(256, N_NODES - node0);
  cur[t] = 0;
  if (t < nn) offl[t] = off[node0 + t];
  __syncthreads();
  int r0 = bbase[b], r1 = bbase[b + 1];
  for (int r = r0 + t; r < r1; r += 256) {
    uint sd = packed[r];
    int d0 = sd >> 17;
    uint src = sd & 0x1FFFFu;
    float w = dis[src];  // L2-hot 400KB gather
    uint w15 = min((uint)(w * 32768.0f + 0.5f), 32767u);
    int pos = offl[d0] + atomicAdd(&cur[d0], 1);
    ep[pos] = src | (w15 << 17);
  }
}

// ---------------- W pre-pack into MFMA B-fragment order (bf16, merged) ----------------

__global__ void k_packW(const float* __restrict__ W1, ushort* __restrict__ Wp1,
                        const float* __restrict__ W2, ushort* __restrict__ Wp2) {
  int t = blockIdx.x * 256 + threadIdx.x;
  if (t < 8 * 8 * 64) {
    int l = t & 63, ks = (t >> 6) & 7, nt = t >> 9;
    int k0 = ks * 32 + (l >> 4) * 8;
    int n = nt * 16 + (l & 15);
    ushort* dst = Wp1 + (size_t)t * 8;
#pragma unroll
    for (int i = 0; i < 8; i++) dst[i] = f2bf(W1[(k0 + i) * DHID + n]);
  } else if (t < 8 * 8 * 64 + 4 * 4 * 64) {
    int t2 = t - 8 * 8 * 64;
    int l = t2 & 63, ks = (t2 >> 6) & 3, nt = t2 >> 8;
    int k0 = ks * 32 + (l >> 4) * 8;
    int n = nt * 16 + (l & 15);
    ushort* dst = Wp2 + (size_t)t2 * 8;
#pragma unroll
    for (int i = 0; i < 8; i++) dst[i] = f2bf(W2[(k0 + i) * DOUT + n]);
  }
}

// ------- FUSED agg1 + GEMM2: 4-stream joint interleave, 16 gathers in flight -------
// Weights accumulate as raw w15; 2^-15 folded into the final per-node multiply.

#define AGG1_BATCH4(eX, pfx)                                                    \
  {                                                                             \
    uint p0 = ep[eX], p1 = ep[eX + 1], p2 = ep[eX + 2], p3 = ep[eX + 3];        \
    ushort v0 = h1[(size_t)(p0 & 0x1FFFFu) * 64 + lane];                        \
    ushort v1 = h1[(size_t)(p1 & 0x1FFFFu) * 64 + lane];                        \
    ushort v2 = h1[(size_t)(p2 & 0x1FFFFu) * 64 + lane];                        \
    ushort v3 = h1[(size_t)(p3 & 0x1FFFFu) * 64 + lane];                        \
    f32x2 f0 = fp8x2f(v0), f1 = fp8x2f(v1), f2 = fp8x2f(v2), f3 = fp8x2f(v3);   \
    float w0 = (float)(p0 >> 17);                                               \
    float w1 = (float)(p1 >> 17);                                               \
    float w2 = (float)(p2 >> 17);                                               \
    float w3 = (float)(p3 >> 17);                                               \
    ax##pfx = fmaf(f0.x, w0, ax##pfx); ay##pfx = fmaf(f0.y, w0, ay##pfx);       \
    ax##pfx = fmaf(f1.x, w1, ax##pfx); ay##pfx = fmaf(f1.y, w1, ay##pfx);       \
    ax##pfx = fmaf(f2.x, w2, ax##pfx); ay##pfx = fmaf(f2.y, w2, ay##pfx);       \
    ax##pfx = fmaf(f3.x, w3, ax##pfx); ay##pfx = fmaf(f3.y, w3, ay##pfx);       \
  }

#define AGG1_TAIL(eX, eX1, pfx)                                                 \
  for (; eX < eX1; eX++) {                                                      \
    uint p = ep[eX];                                                            \
    f32x2 f0 = fp8x2f(h1[(size_t)(p & 0x1FFFFu) * 64 + lane]);                  \
    float w0 = (float)(p >> 17);                                                \
    ax##pfx = fmaf(f0.x, w0, ax##pfx); ay##pfx = fmaf(f0.y, w0, ay##pfx);       \
  }

__global__ __launch_bounds__(256) void k_agg1g2(const ushort* __restrict__ h1,
                                                const int* __restrict__ off,
                                                const uint* __restrict__ ep,
                                                const float* __restrict__ dis,
                                                const float* __restrict__ b1,
                                                const ushort* __restrict__ Wp2,
                                                uchar* __restrict__ h2) {
  __shared__ ushort as[16][136];  // padded: row stride 272 B
  int w = threadIdx.x >> 6, lane = threadIdx.x & 63;
  int nb0 = blockIdx.x * 16;  // 100000 % 16 == 0
  float2 bb = ((const float2*)b1)[lane];
  int widA = nb0 + w * 4;
  float dA = dis[widA], dB = dis[widA + 1], dC = dis[widA + 2], dD = dis[widA + 3];
  f32x2 hvA = fp8x2f(h1[(size_t)widA * 64 + lane]);
  f32x2 hvB = fp8x2f(h1[(size_t)(widA + 1) * 64 + lane]);
  f32x2 hvC = fp8x2f(h1[(size_t)(widA + 2) * 64 + lane]);
  f32x2 hvD = fp8x2f(h1[(size_t)(widA + 3) * 64 + lane]);
  float sA = dA * 32768.0f, sB = dB * 32768.0f, sC = dC * 32768.0f, sD = dD * 32768.0f;
  float axA = hvA.x * sA, ayA = hvA.y * sA;
  float axB = hvB.x * sB, ayB = hvB.y * sB;
  float axC = hvC.x * sC, ayC = hvC.y * sC;
  float axD = hvD.x * sD, ayD = hvD.y * sD;
  int eA  = __builtin_amdgcn_readfirstlane(off[widA]);
  int eA1 = __builtin_amdgcn_readfirstlane(off[widA + 1]);
  int eB  = eA1;
  int eB1 = __builtin_amdgcn_readfirstlane(off[widA + 2]);
  int eC  = eB1;
  int eC1 = __builtin_amdgcn_readfirstlane(off[widA + 3]);
  int eD  = eC1;
  int eD1 = __builtin_amdgcn_readfirstlane(off[widA + 4]);
  while (eA + 4 <= eA1 && eB + 4 <= eB1 && eC + 4 <= eC1 && eD + 4 <= eD1) {
    AGG1_BATCH4(eA, A)
    AGG1_BATCH4(eB, B)
    AGG1_BATCH4(eC, C)
    AGG1_BATCH4(eD, D)
    eA += 4; eB += 4; eC += 4; eD += 4;
  }
  while (eA + 4 <= eA1 && eB + 4 <= eB1) {
    AGG1_BATCH4(eA, A)
    AGG1_BATCH4(eB, B)
    eA += 4; eB += 4;
  }
  while (eC + 4 <= eC1 && eD + 4 <= eD1) {
    AGG1_BATCH4(eC, C)
    AGG1_BATCH4(eD, D)
    eC += 4; eD += 4;
  }
  for (; eA + 4 <= eA1; eA += 4) AGG1_BATCH4(eA, A)
  for (; eB + 4 <= eB1; eB += 4) AGG1_BATCH4(eB, B)
  for (; eC + 4 <= eC1; eC += 4) AGG1_BATCH4(eC, C)
  for (; eD + 4 <= eD1; eD += 4) AGG1_BATCH4(eD, D)
  AGG1_TAIL(eA, eA1, A)
  AGG1_TAIL(eB, eB1, B)
  AGG1_TAIL(eC, eC1, C)
  AGG1_TAIL(eD, eD1, D)
  {
    float rx, ry;
    float fA = dA * 0x1p-15f, fB = dB * 0x1p-15f, fC = dC * 0x1p-15f, fD = dD * 0x1p-15f;
    rx = fmaxf(fmaf(fA, axA, bb.x), 0.f); ry = fmaxf(fmaf(fA, ayA, bb.y), 0.f);
    ((uint*)&as[w * 4 + 0][0])[lane] = (uint)f2bf(rx) | ((uint)f2bf(ry) << 16);
    rx = fmaxf(fmaf(fB, axB, bb.x), 0.f); ry = fmaxf(fmaf(fB, ayB, bb.y), 0.f);
    ((uint*)&as[w * 4 + 1][0])[lane] = (uint)f2bf(rx) | ((uint)f2bf(ry) << 16);
    rx = fmaxf(fmaf(fC, axC, bb.x), 0.f); ry = fmaxf(fmaf(fC, ayC, bb.y), 0.f);
    ((uint*)&as[w * 4 + 2][0])[lane] = (uint)f2bf(rx) | ((uint)f2bf(ry) << 16);
    rx = fmaxf(fmaf(fD, axD, bb.x), 0.f); ry = fmaxf(fmaf(fD, ayD, bb.y), 0.f);
    ((uint*)&as[w * 4 + 3][0])[lane] = (uint)f2bf(rx) | ((uint)f2bf(ry) << 16);
  }
  __syncthreads();
  f32x4 acc = (f32x4)(0.f);
  const bf16x8* wp = (const bf16x8*)Wp2;
#pragma unroll
  for (int ks = 0; ks < 4; ks++) {
    bf16x8 af = *(const bf16x8*)&as[lane & 15][ks * 32 + (lane >> 4) * 8];
    bf16x8 bf = wp[(w * 4 + ks) * 64 + lane];
    acc = __builtin_amdgcn_mfma_f32_16x16x32_bf16(af, bf, acc, 0, 0, 0);
  }
#pragma unroll
  for (int r = 0; r < 4; r++) {
    int row = (lane >> 4) * 4 + r;
    h2[(size_t)(nb0 + row) * DOUT + w * 16 + (lane & 15)] = (uchar)f2fp8(acc[r]);
  }
}

// -- agg2: 4 nodes/wave (16 lanes x 4 dims each) + bias + log_softmax --

#define AGG2_BATCH4(eX)                                                         \
  {                                                                             \
    uint p0 = ep[eX], p1 = ep[eX + 1], p2 = ep[eX + 2], p3 = ep[eX + 3];        \
    uint v0 = h2u[(size_t)(p0 & 0x1FFFFu) * 16 + q];                            \
    uint v1 = h2u[(size_t)(p1 & 0x1FFFFu) * 16 + q];                            \
    uint v2 = h2u[(size_t)(p2 & 0x1FFFFu) * 16 + q];                            \
    uint v3 = h2u[(size_t)(p3 & 0x1FFFFu) * 16 + q];                            \
    float w0 = (float)(p0 >> 17);                                               \
    float w1 = (float)(p1 >> 17);                                               \
    float w2 = (float)(p2 >> 17);                                               \
    float w3 = (float)(p3 >> 17);                                               \
    f32x2 l0 = fp8x2f(v0), h0 = fp8x2f(v0 >> 16);                               \
    f32x2 l1 = fp8x2f(v1), h1_ = fp8x2f(v1 >> 16);                              \
    f32x2 l2 = fp8x2f(v2), h2_ = fp8x2f(v2 >> 16);                              \
    f32x2 l3 = fp8x2f(v3), h3_ = fp8x2f(v3 >> 16);                              \
    a0 = fmaf(l0.x, w0, a0); a1 = fmaf(l0.y, w0, a1);                           \
    a2 = fmaf(h0.x, w0, a2); a3 = fmaf(h0.y, w0, a3);                           \
    a0 = fmaf(l1.x, w1, a0); a1 = fmaf(l1.y, w1, a1);                           \
    a2 = fmaf(h1_.x, w1, a2); a3 = fmaf(h1_.y, w1, a3);                         \
    a0 = fmaf(l2.x, w2, a0); a1 = fmaf(l2.y, w2, a1);                           \
    a2 = fmaf(h2_.x, w2, a2); a3 = fmaf(h2_.y, w2, a3);                         \
    a0 = fmaf(l3.x, w3, a0); a1 = fmaf(l3.y, w3, a1);                           \
    a2 = fmaf(h3_.x, w3, a2); a3 = fmaf(h3_.y, w3, a3);                         \
  }

__global__ __launch_bounds__(256) void k_agg2(const uint* __restrict__ h2u,
                                              const int* __restrict__ off,
                                              const uint* __restrict__ ep,
                                              const float* __restrict__ dis,
                                              const float* __restrict__ b2,
                                              float* __restrict__ out) {
  int gw   = (blockIdx.x * 256 + threadIdx.x) >> 6;  // wave id
  int lane = threadIdx.x & 63;
  int g = lane >> 4;       // node group 0..3
  int q = lane & 15;       // handles dims 4q..4q+3
  int wid = gw * 4 + g;    // N % 4 == 0 -> all waves full
  if (wid >= N_NODES) return;
  float d = dis[wid];
  uint sv = h2u[(size_t)wid * 16 + q];
  f32x2 slo = fp8x2f(sv), shi = fp8x2f(sv >> 16);
  float dS = d * 32768.0f;
  float a0 = slo.x * dS, a1 = slo.y * dS, a2 = shi.x * dS, a3 = shi.y * dS;
  int o0 = off[wid], o1 = off[wid + 1];  // uniform within 16-lane group
  int e = o0;
  for (; e + 4 <= o1; e += 4) AGG2_BATCH4(e)
  for (; e < o1; e++) {
    uint p = ep[e];
    uint v = h2u[(size_t)(p & 0x1FFFFu) * 16 + q];
    float w = (float)(p >> 17);
    f32x2 lo = fp8x2f(v), hi = fp8x2f(v >> 16);
    a0 = fmaf(lo.x, w, a0); a1 = fmaf(lo.y, w, a1);
    a2 = fmaf(hi.x, w, a2); a3 = fmaf(hi.y, w, a3);
  }
  float4 bbv = ((const float4*)b2)[q];
  float ds = d * 0x1p-15f;
  float v0 = fmaf(ds, a0, bbv.x);
  float v1 = fmaf(ds, a1, bbv.y);
  float v2 = fmaf(ds, a2, bbv.z);
  float v3 = fmaf(ds, a3, bbv.w);
  // log_softmax over 64 dims = 16 lanes x 4; xor 1,2,4,8 stays within group
  float m = fmaxf(fmaxf(v0, v1), fmaxf(v2, v3));
#pragma unroll
  for (int sft = 8; sft >= 1; sft >>= 1) m = fmaxf(m, __shfl_xor(m, sft, 64));
  float sum = expf(v0 - m) + expf(v1 - m) + expf(v2 - m) + expf(v3 - m);
#pragma unroll
  for (int sft = 8; sft >= 1; sft >>= 1) sum += __shfl_xor(sum, sft, 64);
  float ls = m + logf(sum);
  float4 o;
  o.x = v0 - ls; o.y = v1 - ls; o.z = v2 - ls; o.w = v3 - ls;
  ((float4*)out)[(size_t)wid * 16 + q] = o;
}

// ---------------- launch ----------------

extern "C" void kernel_launch(void* const* d_in, const int* in_sizes, int n_in,
                              void* d_out, int out_size, void* d_ws, size_t ws_size,
                              hipStream_t stream) {
  const float* x  = (const float*)d_in[0];
  const int*   ei = (const int*)d_in[1];
  const float* W1 = (const float*)d_in[2];
  const float* b1 = (const float*)d_in[3];
  const float* W2 = (const float*)d_in[4];
  const float* b2 = (const float*)d_in[5];
  float* out = (float*)d_out;
  const int* rowp = ei;            // sources
  const int* colp = ei + N_EDGES;  // destinations

  char* p = (char*)d_ws;
  size_t o = 0;
  auto alloc = [&](size_t bytes) -> void* {
    void* r = p + o;
    o = (o + bytes + 255) & ~(size_t)255;
    return r;
  };
  int*    off    = (int*)alloc((size_t)(N_NODES + 1) * 4);
  float*  dis    = (float*)alloc((size_t)N_NODES * 4);
  int*    cntmat = (int*)alloc((size_t)NCHUNK * NBUCKET * 4);
  int*    basemat= (int*)alloc((size_t)NCHUNK * NBUCKET * 4);
  int*    btot   = (int*)alloc((size_t)NBUCKET * 4);
  int*    bbase  = (int*)alloc((size_t)(NBUCKET + 1) * 4);
  uint*   packed = (uint*)alloc((size_t)N_EDGES * 4);
  uint*   ep     = (uint*)alloc((size_t)N_EDGES * 4);
  ushort* Wp1    = (ushort*)alloc((size_t)8 * 8 * 64 * 8 * 2);
  ushort* Wp2    = (ushort*)alloc((size_t)4 * 4 * 64 * 8 * 2);
  uchar*  h1     = (uchar*)alloc((size_t)N_NODES * DHID);   // 12.8 MB fp8
  uchar*  h2     = (uchar*)alloc((size_t)N_NODES * DOUT);   // 6.4 MB fp8

  k_packW<<<20, 256, 0, stream>>>(W1, Wp1, W2, Wp2);
  k_hist_g<<<NCHUNK + G_HIST, 256, 0, stream>>>(colp, cntmat, x, Wp1, h1);
  k_buckettot<<<NBUCKET, 256, 0, stream>>>(cntmat, btot);
  k_chunkpfx<<<(NBUCKET + 3) / 4, 256, 0, stream>>>(cntmat, btot, bbase, basemat);
  k_binscatter_g<<<NCHUNK + G_BINS, 256, 0, stream>>>(rowp, colp, basemat, packed, x, Wp1, h1);
  k_count256_g<<<NBUCKET + G_CNT, 256, 0, stream>>>(packed, bbase, off, dis, x, Wp1, h1);
  k_place_g<<<NBUCKET + G_PLC, 256, 0, stream>>>(packed, bbase, off, dis, ep, x, Wp1, h1);
  k_agg1g2<<<N_NODES / 16, 256, 0, stream>>>((const ushort*)h1, off, ep, dis, b1, Wp2, h2);
  k_agg2<<<N_NODES / 16, 256, 0, stream>>>((const uint*)h2, off, ep, dis, b2, out);
}